// Round 13
// baseline (133755.652 us; speedup 1.0000x reference)
//
#include <hip/hip_runtime.h>

#define TT    1024
#define NTHR  512
#define NWG   256

// ---- per-XCD state block (float offsets within block) ----
#define XB_SZ  65536           // floats per XCD (256 KB)
#define XA0    0               // ahx0: 2 x 8 x 128
#define XA1    2048            // ahx1: 2 x 8 x 128
#define XF0    4096            // fhx0: 2 x 8 x 512
#define XF1    12288           // fhx1: 2 x 8 x 512
#define XP0    20480           // pol0: 8 x 2560
#define XP1    40960           // pol1: 8 x 2560
#define X_ZERO_END 20480

#define O_BARB (8 * XB_SZ)     // barrier block float offset
// bar ints: cnt[xcd]=xcd*256, epoch[xcd]=xcd*256+64, roster[xcd]=2048+xcd

// ---- LDS: two phase-weight buffers ----
// LSTM layout: 16 rows (rr=q*4+jj) x 1156 (1152 used: 512 x | 512 h | 128 a)
// aRNN layout: 32 rows (fwi c4 | fwh 16+c4) x 516 (512 used)
// pol  layout: 80 rows x 132 (128 used)
#define BUF_FL 18496           // 72.25 KB; x2 = 144.5 KB -> 1 WG/CU

__device__ __forceinline__ float sigm(float x) { return 1.f / (1.f + __expf(-x)); }

__device__ __forceinline__ float dot_ks(const float* __restrict__ a,
                                        const float* __restrict__ w,
                                        int nq, int ks) {
  float s0=0.f,s1=0.f,s2=0.f,s3=0.f;
  const float4* a4=(const float4*)a; const float4* w4=(const float4*)w;
  #pragma unroll 8
  for (int k = 0; k < nq; ++k) {
    int i4 = (k<<2) + ks;
    float4 av = a4[i4], wv = w4[i4];
    s0=fmaf(av.x,wv.x,s0); s1=fmaf(av.y,wv.y,s1);
    s2=fmaf(av.z,wv.z,s2); s3=fmaf(av.w,wv.w,s3);
  }
  return (s0+s1)+(s2+s3);
}
__device__ __forceinline__ float dot3_ks(const float* __restrict__ a,
                                         const float* __restrict__ pp,
                                         const float* __restrict__ w,
                                         int nq, int ks) {
  float s0=0.f,s1=0.f,s2=0.f,s3=0.f;
  const float4* a4=(const float4*)a; const float4* p4=(const float4*)pp;
  const float4* w4=(const float4*)w;
  #pragma unroll 8
  for (int k = 0; k < nq; ++k) {
    int i4 = (k<<2) + ks;
    float4 av = a4[i4], pv = p4[i4], wv = w4[i4];
    s0=fmaf(av.x*pv.x,wv.x,s0); s1=fmaf(av.y*pv.y,wv.y,s1);
    s2=fmaf(av.z*pv.z,wv.z,s2); s3=fmaf(av.w*pv.w,wv.w,s3);
  }
  return (s0+s1)+(s2+s3);
}
__device__ __forceinline__ float dot_full(const float* __restrict__ a,
                                          const float* __restrict__ w) {
  float s0=0.f,s1=0.f,s2=0.f,s3=0.f;
  const float4* a4=(const float4*)a; const float4* w4=(const float4*)w;
  #pragma unroll 8
  for (int k = 0; k < 32; ++k) {
    float4 av = a4[k], wv = w4[k];
    s0=fmaf(av.x,wv.x,s0); s1=fmaf(av.y,wv.y,s1);
    s2=fmaf(av.z,wv.z,s2); s3=fmaf(av.w,wv.w,s3);
  }
  return (s0+s1)+(s2+s3);
}

// ---- weight staging: global -> regs (issue early) -> LDS (commit late) ----
// LSTM: 4608 f4 chunks; chunk c: rr=c/288, cq=c%288; lds f4 = rr*289+cq.
__device__ __forceinline__ void stg_lstm_ld(const float* Wih, int r, float4* st, int tid) {
  const float4* g = (const float4*)Wih;
  #pragma unroll
  for (int k = 0; k < 9; ++k) {
    int c = tid + k * 512;
    int rr = c / 288, cq = c - rr * 288;
    int grow = (rr >> 2) * 128 + r * 4 + (rr & 3);
    st[k] = g[(size_t)grow * 288 + cq];
  }
}
__device__ __forceinline__ void stg_lstm_wr(float* buf, const float4* st, int tid) {
  #pragma unroll
  for (int k = 0; k < 9; ++k) {
    int c = tid + k * 512;
    int rr = c / 288, cq = c - rr * 288;
    *(float4*)(buf + rr * 1156 + cq * 4) = st[k];
  }
}
// pol: 2560 f4; chunk c: rw=c>>5, cq=c&31; lds f4 = rw*33+cq.
__device__ __forceinline__ void stg_pol_ld(const float* pW, int r, float4* st, int tid) {
  const float4* g = (const float4*)pW;
  #pragma unroll
  for (int k = 0; k < 5; ++k) {
    int c = tid + k * 512;
    int rw = c >> 5, cq = c & 31;
    st[k] = g[(size_t)(r * 80 + rw) * 32 + cq];
  }
}
__device__ __forceinline__ void stg_pol_wr(float* buf, const float4* st, int tid) {
  #pragma unroll
  for (int k = 0; k < 5; ++k) {
    int c = tid + k * 512;
    int rw = c >> 5, cq = c & 31;
    *(float4*)(buf + rw * 132 + cq * 4) = st[k];
  }
}
// aRNN: 4096 f4; chunk c: rw=c>>7 (0-15 ih, 16-31 hh), cq=c&127; lds f4=rw*129+cq.
__device__ __forceinline__ void stg_arnn_ld(const float* Wih, const float* Whh,
                                            int r, float4* st, int tid) {
  #pragma unroll
  for (int k = 0; k < 8; ++k) {
    int c = tid + k * 512;
    int rw = c >> 7, cq = c & 127;
    const float4* g = (const float4*)((rw < 16) ? Wih : Whh);
    st[k] = g[(size_t)(r * 16 + (rw & 15)) * 128 + cq];
  }
}
__device__ __forceinline__ void stg_arnn_wr(float* buf, const float4* st, int tid) {
  #pragma unroll
  for (int k = 0; k < 8; ++k) {
    int c = tid + k * 512;
    int rw = c >> 7, cq = c & 127;
    *(float4*)(buf + rw * 516 + cq * 4) = st[k];
  }
}

// ---- intra-XCD barrier (R12-proven) ----
__device__ __forceinline__ void xbar(int* cnt, int* ep, int e, int tid) {
  __syncthreads();
  if (tid == 0) {
    int old = __hip_atomic_fetch_add(cnt, 1, __ATOMIC_RELAXED,
                                     __HIP_MEMORY_SCOPE_AGENT);
    if (old == e * 32 - 1)
      __hip_atomic_store(ep, e, __ATOMIC_RELAXED, __HIP_MEMORY_SCOPE_AGENT);
    while (__hip_atomic_load(ep, __ATOMIC_RELAXED,
                             __HIP_MEMORY_SCOPE_AGENT) < e)
      __builtin_amdgcn_s_sleep(1);
    (void)__hip_atomic_load(ep, __ATOMIC_ACQUIRE, __HIP_MEMORY_SCOPE_AGENT);
  }
  __syncthreads();
}

struct Params {
  const float* x;
  const float *aW_ih0, *aW_hh0, *ab_ih0, *ab_hh0, *pW0, *pb0, *fW_ih0, *fW_hh0, *fb0;
  const float *aW_ih1, *aW_hh1, *ab_ih1, *ab_hh1, *pW1, *pb1, *fW_ih1, *fW_hh1, *fb1;
  float* out;
  float* ws;
};

__global__ __launch_bounds__(NTHR, 1)
void arnn_kernel(Params p) {
  extern __shared__ float lds[];
  __shared__ int s_rank;
  const int tid = threadIdx.x;
  float* __restrict__ ws = p.ws;

  int xcd;
  asm volatile("s_getreg_b32 %0, hwreg(HW_REG_XCC_ID)" : "=s"(xcd));
  xcd &= 7;

  int* bar = (int*)(ws + O_BARB);
  if (tid == 0)
    s_rank = __hip_atomic_fetch_add(&bar[2048 + xcd], 1,
                                    __ATOMIC_RELAXED, __HIP_MEMORY_SCOPE_AGENT);
  __syncthreads();
  const int r = s_rank;
  int* cnt = &bar[xcd * 256];
  int* ep  = &bar[xcd * 256 + 64];

  float* xb = ws + (size_t)xcd * XB_SZ;
  const int b0 = xcd * 8;

  for (int i = r * NTHR + tid; i < X_ZERO_END; i += 32 * NTHR) xb[i] = 0.f;

  // ---- thread maps (R12-proven) ----
  const int lane = tid & 63;
  const int ks   = tid & 3;
  const int jj = tid >> 7, blL = (tid >> 4) & 7, q = (tid >> 2) & 3;
  const int jL = r * 4 + jj;
  const bool cell = (tid & 15) == 0;
  const int c4 = tid >> 5, blA = (tid >> 2) & 7;
  const int cA = r * 16 + c4;
  const int nAr = tid >> 3, blP = tid & 7;     // pol LDS row = nAr / 64+nAr
  const int nA = r * 80 + nAr;
  const int nB = r * 80 + 64 + nAr;            // valid if tid < 128

  float bi0=0,bf0=0,bg0=0,bo0=0, bi1=0,bf1=0,bg1=0,bo1=0;
  if (cell) {
    bi0 = p.ab_ih0[0*128+jL] + p.ab_hh0[0*128+jL];
    bf0 = p.ab_ih0[1*128+jL] + p.ab_hh0[1*128+jL];
    bg0 = p.ab_ih0[2*128+jL] + p.ab_hh0[2*128+jL];
    bo0 = p.ab_ih0[3*128+jL] + p.ab_hh0[3*128+jL];
    bi1 = p.ab_ih1[0*128+jL] + p.ab_hh1[0*128+jL];
    bf1 = p.ab_ih1[1*128+jL] + p.ab_hh1[1*128+jL];
    bg1 = p.ab_ih1[2*128+jL] + p.ab_hh1[2*128+jL];
    bo1 = p.ab_ih1[3*128+jL] + p.ab_hh1[3*128+jL];
  }
  const float fb0c = p.fb0[cA], fb1c = p.fb1[cA];
  const float pb0a = p.pb0[nA], pb1a = p.pb1[nA];
  float pb0b = 0.f, pb1b = 0.f;
  if (tid < 128) { pb0b = p.pb0[nB]; pb1b = p.pb1[nB]; }

  // streamed (not staged): whh rows
  const int rowL = q * 128 + jL;
  const float* whh0 = p.aW_hh0 + (size_t)rowL * 128;
  const float* whh1 = p.aW_hh1 + (size_t)rowL * 128;

  float creg0 = 0.f, creg1 = 0.f;
  float4 st[9];

  // ---- prologue: stage LSTM0 weights into buf0 ----
  stg_lstm_ld(p.aW_ih0, r, st, tid);
  stg_lstm_wr(lds, st, tid);

  int e = 1;
  xbar(cnt, ep, e, tid);

  for (int t = 0; t < TT; ++t) {
    const int old = t & 1, nw = old ^ 1;
    float* ahx0_o = xb + XA0 + old * 1024;
    float* ahx0_n = xb + XA0 + nw  * 1024;
    float* ahx1_o = xb + XA1 + old * 1024;
    float* ahx1_n = xb + XA1 + nw  * 1024;
    float* fhx0_o = xb + XF0 + old * 4096;
    float* fhx0_n = xb + XF0 + nw  * 4096;
    float* fhx1_o = xb + XF1 + old * 4096;
    float* fhx1_n = xb + XF1 + nw  * 4096;
    float* pol0   = xb + XP0;
    float* pol1   = xb + XP1;
    const float* xt = p.x + ((size_t)t * 64 + b0) * 512;

    // ---- P0: LSTM0 (buf0) ; stage pol0 -> buf1 ----
    stg_pol_ld(p.pW0, r, st, tid);
    {
      const float* w = lds + (q * 4 + jj) * 1156;
      float s = dot_ks(xt     + blL * 512, w,        32, ks)
              + dot_ks(fhx0_o + blL * 512, w + 512,  32, ks)
              + dot_ks(ahx1_o + blL * 128, w + 1024,  8, ks)
              + dot_ks(ahx0_o + blL * 128, whh0,      8, ks);
      s += __shfl_xor(s, 1); s += __shfl_xor(s, 2);
      float gi = __shfl(s,(lane&48)+0),  gf = __shfl(s,(lane&48)+4);
      float gg = __shfl(s,(lane&48)+8),  go = __shfl(s,(lane&48)+12);
      if (cell) {
        gi += bi0; gf += bf0; gg += bg0; go += bo0;
        float c2 = sigm(gf) * creg0 + sigm(gi) * tanhf(gg);
        creg0 = c2;
        ahx0_n[blL * 128 + jL] = sigm(go) * tanhf(c2);
      }
    }
    stg_pol_wr(lds + BUF_FL, st, tid);
    ++e; xbar(cnt, ep, e, tid);

    // ---- P1: pol0 (buf1) ; stage aRNN0 -> buf0 ----
    stg_arnn_ld(p.fW_ih0, p.fW_hh0, r, st, tid);
    {
      const float* Lb = lds + BUF_FL;
      pol0[blP * 2560 + nA] = pb0a + dot_full(ahx0_n + blP * 128, Lb + nAr * 132);
      if (tid < 128)
        pol0[blP * 2560 + nB] = pb0b + dot_full(ahx0_n + blP * 128, Lb + (64 + nAr) * 132);
    }
    stg_arnn_wr(lds, st, tid);
    ++e; xbar(cnt, ep, e, tid);

    // ---- P2: aRNN0 (buf0) ; stage LSTM1 -> buf1 ----
    stg_lstm_ld(p.aW_ih1, r, st, tid);
    {
      const float* wi = lds + c4 * 516;
      const float* wh = lds + (16 + c4) * 516;
      const float* pr = pol0 + blA * 2560;
      float sig = dot3_ks(xt     + blA * 512, pr,       wi, 32, ks);
      float shg = dot3_ks(fhx0_o + blA * 512, pr + 512, wh, 32, ks);
      sig += __shfl_xor(sig, 1); sig += __shfl_xor(sig, 2);
      shg += __shfl_xor(shg, 1); shg += __shfl_xor(shg, 2);
      if (ks == 0) {
        float v = tanhf(sig * pr[1024 + cA] + fb0c * pr[2048 + cA]
                      + shg * pr[1536 + cA]);
        fhx0_n[blA * 512 + cA] = v;
      }
    }
    stg_lstm_wr(lds + BUF_FL, st, tid);
    ++e; xbar(cnt, ep, e, tid);

    // ---- P3: LSTM1 (buf1) ; stage pol1 -> buf0 ----
    stg_pol_ld(p.pW1, r, st, tid);
    {
      const float* w = lds + BUF_FL + (q * 4 + jj) * 1156;
      float s = dot_ks(fhx0_n + blL * 512, w,        32, ks)
              + dot_ks(fhx1_o + blL * 512, w + 512,  32, ks)
              + dot_ks(ahx0_n + blL * 128, w + 1024,  8, ks)
              + dot_ks(ahx1_o + blL * 128, whh1,      8, ks);
      s += __shfl_xor(s, 1); s += __shfl_xor(s, 2);
      float gi = __shfl(s,(lane&48)+0),  gf = __shfl(s,(lane&48)+4);
      float gg = __shfl(s,(lane&48)+8),  go = __shfl(s,(lane&48)+12);
      if (cell) {
        gi += bi1; gf += bf1; gg += bg1; go += bo1;
        float c2 = sigm(gf) * creg1 + sigm(gi) * tanhf(gg);
        creg1 = c2;
        ahx1_n[blL * 128 + jL] = sigm(go) * tanhf(c2);
      }
    }
    stg_pol_wr(lds, st, tid);
    ++e; xbar(cnt, ep, e, tid);

    // ---- P4: pol1 (buf0) ; stage aRNN1 -> buf1 ----
    stg_arnn_ld(p.fW_ih1, p.fW_hh1, r, st, tid);
    {
      pol1[blP * 2560 + nA] = pb1a + dot_full(ahx1_n + blP * 128, lds + nAr * 132);
      if (tid < 128)
        pol1[blP * 2560 + nB] = pb1b + dot_full(ahx1_n + blP * 128, lds + (64 + nAr) * 132);
    }
    stg_arnn_wr(lds + BUF_FL, st, tid);
    ++e; xbar(cnt, ep, e, tid);

    // ---- P5: aRNN1 + output (buf1) ; stage LSTM0 -> buf0 (next step) ----
    stg_lstm_ld(p.aW_ih0, r, st, tid);
    {
      const float* wi = lds + BUF_FL + c4 * 516;
      const float* wh = lds + BUF_FL + (16 + c4) * 516;
      const float* pr = pol1 + blA * 2560;
      float sig = dot3_ks(fhx0_n + blA * 512, pr,       wi, 32, ks);
      float shg = dot3_ks(fhx1_o + blA * 512, pr + 512, wh, 32, ks);
      sig += __shfl_xor(sig, 1); sig += __shfl_xor(sig, 2);
      shg += __shfl_xor(shg, 1); shg += __shfl_xor(shg, 2);
      if (ks == 0) {
        float v = tanhf(sig * pr[1024 + cA] + fb1c * pr[2048 + cA]
                      + shg * pr[1536 + cA]);
        fhx1_n[blA * 512 + cA] = v;
        p.out[((size_t)t * 64 + b0 + blA) * 512 + cA] = v;
      }
    }
    stg_lstm_wr(lds, st, tid);
    ++e; xbar(cnt, ep, e, tid);
  }
}

extern "C" void kernel_launch(void* const* d_in, const int* in_sizes, int n_in,
                              void* d_out, int out_size, void* d_ws, size_t ws_size,
                              hipStream_t stream) {
  Params prm;
  prm.x      = (const float*)d_in[0];
  prm.aW_ih0 = (const float*)d_in[1];
  prm.aW_hh0 = (const float*)d_in[2];
  prm.ab_ih0 = (const float*)d_in[3];
  prm.ab_hh0 = (const float*)d_in[4];
  prm.pW0    = (const float*)d_in[5];
  prm.pb0    = (const float*)d_in[6];
  prm.fW_ih0 = (const float*)d_in[7];
  prm.fW_hh0 = (const float*)d_in[8];
  prm.fb0    = (const float*)d_in[9];
  prm.aW_ih1 = (const float*)d_in[10];
  prm.aW_hh1 = (const float*)d_in[11];
  prm.ab_ih1 = (const float*)d_in[12];
  prm.ab_hh1 = (const float*)d_in[13];
  prm.pW1    = (const float*)d_in[14];
  prm.pb1    = (const float*)d_in[15];
  prm.fW_ih1 = (const float*)d_in[16];
  prm.fW_hh1 = (const float*)d_in[17];
  prm.fb1    = (const float*)d_in[18];
  prm.out    = (float*)d_out;
  prm.ws     = (float*)d_ws;

  hipMemsetAsync((char*)d_ws + (size_t)O_BARB * 4, 0, 16384, stream);

  static int lds_bytes = 2 * BUF_FL * 4;   // 148 KB -> 1 WG/CU
  hipFuncSetAttribute((const void*)arnn_kernel,
                      hipFuncAttributeMaxDynamicSharedMemorySize, lds_bytes);

  void* kargs[] = { (void*)&prm };
  hipLaunchCooperativeKernel((const void*)arnn_kernel, dim3(NWG), dim3(NTHR),
                             kargs, lds_bytes, stream);
}

// Round 14
// 118925.305 us; speedup vs baseline: 1.1247x; 1.1247x over previous
//
#include <hip/hip_runtime.h>

#define TT    1024
#define NTHR  512
#define NWG   256

// ---- per-XCD state block (float offsets within block) ----
#define XB_SZ  65536           // floats per XCD (256 KB)
#define XA0    0               // ahx0: 2 x 8 x 128
#define XA1    2048            // ahx1: 2 x 8 x 128
#define XF0    4096            // fhx0: 2 x 8 x 512
#define XF1    12288           // fhx1: 2 x 8 x 512
#define XP0    20480           // pol0: 8 x 2560
#define XP1    40960           // pol1: 8 x 2560
#define X_ZERO_END 20480

#define O_BARB (8 * XB_SZ)     // barrier block float offset
// bar ints: cnt[xcd]=xcd*256, epoch[xcd]=xcd*256+64, roster[xcd]=2048+xcd

// ---- LDS: two 72 KB slots, 2-colored across the 6-phase weight cycle ----
// slot usage: slotA={LSTM0, aRNN0, pol1}, slotB={pol0, LSTM1, aRNN1}
// LSTM layout: 16 rows x 1152 floats (288 f4), source-swizzled s^(2q), q=row>>2
// aRNN layout: 32 rows x 512 floats (128 f4), linear (2-way conflicts = free)
// pol  layout: 80 rows x 128 floats (32 f4), source-swizzled s^(row&7)
#define SLOT_FL 18432          // 72 KB per slot; 2 slots = 144 KB -> 1 WG/CU

__device__ __forceinline__ float sigm(float x) { return 1.f / (1.f + __expf(-x)); }

// async global->LDS, 16B per lane, zero VGPR data movement
__device__ __forceinline__ void gld_lds(const float* g, float* l) {
  __builtin_amdgcn_global_load_lds(
      (const __attribute__((address_space(1))) void*)g,
      (__attribute__((address_space(3))) void*)l, 16, 0, 0);
}

// streamed-global dot (whh rows only)
__device__ __forceinline__ float dot_ks(const float* __restrict__ a,
                                        const float* __restrict__ w,
                                        int nq, int ks) {
  float s0=0.f,s1=0.f,s2=0.f,s3=0.f;
  const float4* a4=(const float4*)a; const float4* w4=(const float4*)w;
  #pragma unroll 8
  for (int k = 0; k < nq; ++k) {
    int i4 = (k<<2) + ks;
    float4 av = a4[i4], wv = w4[i4];
    s0=fmaf(av.x,wv.x,s0); s1=fmaf(av.y,wv.y,s1);
    s2=fmaf(av.z,wv.z,s2); s3=fmaf(av.w,wv.w,s3);
  }
  return (s0+s1)+(s2+s3);
}
// LDS dot with XOR-swizzled weight index (LSTM segments)
__device__ __forceinline__ float dot_lx(const float* __restrict__ a,
                                        const float4* __restrict__ w4,
                                        int nq, int ks, int xr) {
  float s0=0.f,s1=0.f,s2=0.f,s3=0.f;
  const float4* a4=(const float4*)a;
  #pragma unroll 8
  for (int k = 0; k < nq; ++k) {
    int t = (k<<2) + ks;
    float4 av = a4[t];
    float4 wv = w4[t ^ xr];
    s0=fmaf(av.x,wv.x,s0); s1=fmaf(av.y,wv.y,s1);
    s2=fmaf(av.z,wv.z,s2); s3=fmaf(av.w,wv.w,s3);
  }
  return (s0+s1)+(s2+s3);
}
// LDS dot3 (aRNN; linear layout)
__device__ __forceinline__ float dot3_ks(const float* __restrict__ a,
                                         const float* __restrict__ pp,
                                         const float* __restrict__ w,
                                         int nq, int ks) {
  float s0=0.f,s1=0.f,s2=0.f,s3=0.f;
  const float4* a4=(const float4*)a; const float4* p4=(const float4*)pp;
  const float4* w4=(const float4*)w;
  #pragma unroll 8
  for (int k = 0; k < nq; ++k) {
    int i4 = (k<<2) + ks;
    float4 av = a4[i4], pv = p4[i4], wv = w4[i4];
    s0=fmaf(av.x*pv.x,wv.x,s0); s1=fmaf(av.y*pv.y,wv.y,s1);
    s2=fmaf(av.z*pv.z,wv.z,s2); s3=fmaf(av.w*pv.w,wv.w,s3);
  }
  return (s0+s1)+(s2+s3);
}
// LDS pol dot with XOR-swizzled weight index
__device__ __forceinline__ float dot_pol(const float* __restrict__ a,
                                         const float* __restrict__ w,
                                         int xr) {
  float s0=0.f,s1=0.f,s2=0.f,s3=0.f;
  const float4* a4=(const float4*)a; const float4* w4=(const float4*)w;
  #pragma unroll 8
  for (int k = 0; k < 32; ++k) {
    float4 av = a4[k], wv = w4[k ^ xr];
    s0=fmaf(av.x,wv.x,s0); s1=fmaf(av.y,wv.y,s1);
    s2=fmaf(av.z,wv.z,s2); s3=fmaf(av.w,wv.w,s3);
  }
  return (s0+s1)+(s2+s3);
}

// ---- staging: issue async loads for next phase's weights ----
// LSTM: 4608 f4 = 72 chunks; source row grow=(rr>>2)*128+r*4+(rr&3), slot s^(2q)
__device__ __forceinline__ void stage_lstm(const float* W, float* buf,
                                           int r, int wv, int lane) {
  #pragma unroll
  for (int ci = 0; ci < 9; ++ci) {
    int c = wv * 9 + ci;
    int f4 = c * 64 + lane;
    int rr = f4 / 288, sp = f4 - rr * 288;
    int s  = sp ^ ((rr >> 2) << 1);
    int grow = (rr >> 2) * 128 + r * 4 + (rr & 3);
    gld_lds(W + ((size_t)grow * 288 + s) * 4, buf + (size_t)c * 256);
  }
}
// pol: 2560 f4 = 40 chunks; slot s^(row&7)
__device__ __forceinline__ void stage_pol(const float* pW, float* buf,
                                          int r, int wv, int lane) {
  #pragma unroll
  for (int ci = 0; ci < 5; ++ci) {
    int c = wv * 5 + ci;
    int f4 = c * 64 + lane;
    int nr = f4 >> 5, sp = f4 & 31;
    int s  = sp ^ (nr & 7);
    gld_lds(pW + ((size_t)(r * 80 + nr) * 32 + s) * 4, buf + (size_t)c * 256);
  }
}
// aRNN: 4096 f4 = 64 chunks; rows 0-15 = fW_ih, 16-31 = fW_hh; linear
__device__ __forceinline__ void stage_arnn(const float* Wih, const float* Whh,
                                           float* buf, int r, int wv, int lane) {
  #pragma unroll
  for (int ci = 0; ci < 8; ++ci) {
    int c = wv * 8 + ci;
    int f4 = c * 64 + lane;
    int rw = f4 >> 7, cq = f4 & 127;
    const float* g = (rw < 16)
        ? Wih + ((size_t)(r * 16 + rw) * 128 + cq) * 4
        : Whh + ((size_t)(r * 16 + rw - 16) * 128 + cq) * 4;
    gld_lds(g, buf + (size_t)c * 256);
  }
}

// ---- intra-XCD barrier (R12-proven) ----
__device__ __forceinline__ void xbar(int* cnt, int* ep, int e, int tid) {
  __syncthreads();
  if (tid == 0) {
    int old = __hip_atomic_fetch_add(cnt, 1, __ATOMIC_RELAXED,
                                     __HIP_MEMORY_SCOPE_AGENT);
    if (old == e * 32 - 1)
      __hip_atomic_store(ep, e, __ATOMIC_RELAXED, __HIP_MEMORY_SCOPE_AGENT);
    while (__hip_atomic_load(ep, __ATOMIC_RELAXED,
                             __HIP_MEMORY_SCOPE_AGENT) < e)
      __builtin_amdgcn_s_sleep(1);
    (void)__hip_atomic_load(ep, __ATOMIC_ACQUIRE, __HIP_MEMORY_SCOPE_AGENT);
  }
  __syncthreads();
}

struct Params {
  const float* x;
  const float *aW_ih0, *aW_hh0, *ab_ih0, *ab_hh0, *pW0, *pb0, *fW_ih0, *fW_hh0, *fb0;
  const float *aW_ih1, *aW_hh1, *ab_ih1, *ab_hh1, *pW1, *pb1, *fW_ih1, *fW_hh1, *fb1;
  float* out;
  float* ws;
};

__global__ __launch_bounds__(NTHR, 1)
void arnn_kernel(Params p) {
  extern __shared__ float lds[];
  __shared__ int s_rank;
  const int tid = threadIdx.x;
  float* __restrict__ ws = p.ws;

  int xcd;
  asm volatile("s_getreg_b32 %0, hwreg(HW_REG_XCC_ID)" : "=s"(xcd));
  xcd &= 7;

  int* bar = (int*)(ws + O_BARB);
  if (tid == 0)
    s_rank = __hip_atomic_fetch_add(&bar[2048 + xcd], 1,
                                    __ATOMIC_RELAXED, __HIP_MEMORY_SCOPE_AGENT);
  __syncthreads();
  const int r = s_rank;
  int* cnt = &bar[xcd * 256];
  int* ep  = &bar[xcd * 256 + 64];

  float* xb = ws + (size_t)xcd * XB_SZ;
  const int b0 = xcd * 8;

  for (int i = r * NTHR + tid; i < X_ZERO_END; i += 32 * NTHR) xb[i] = 0.f;

  // ---- thread maps (R12-proven) ----
  const int lane = tid & 63;
  const int wv   = tid >> 6;
  const int ks   = tid & 3;
  const int jj = tid >> 7, blL = (tid >> 4) & 7, q = (tid >> 2) & 3;
  const int jL = r * 4 + jj;
  const bool cell = (tid & 15) == 0;
  const int c4 = tid >> 5, blA = (tid >> 2) & 7;
  const int cA = r * 16 + c4;
  const int nAr = tid >> 3, blP = tid & 7;
  const int nA = r * 80 + nAr;
  const int nB = r * 80 + 64 + nAr;            // valid if tid < 128

  float bi0=0,bf0=0,bg0=0,bo0=0, bi1=0,bf1=0,bg1=0,bo1=0;
  if (cell) {
    bi0 = p.ab_ih0[0*128+jL] + p.ab_hh0[0*128+jL];
    bf0 = p.ab_ih0[1*128+jL] + p.ab_hh0[1*128+jL];
    bg0 = p.ab_ih0[2*128+jL] + p.ab_hh0[2*128+jL];
    bo0 = p.ab_ih0[3*128+jL] + p.ab_hh0[3*128+jL];
    bi1 = p.ab_ih1[0*128+jL] + p.ab_hh1[0*128+jL];
    bf1 = p.ab_ih1[1*128+jL] + p.ab_hh1[1*128+jL];
    bg1 = p.ab_ih1[2*128+jL] + p.ab_hh1[2*128+jL];
    bo1 = p.ab_ih1[3*128+jL] + p.ab_hh1[3*128+jL];
  }
  const float fb0c = p.fb0[cA], fb1c = p.fb1[cA];
  const float pb0a = p.pb0[nA], pb1a = p.pb1[nA];
  float pb0b = 0.f, pb1b = 0.f;
  if (tid < 128) { pb0b = p.pb0[nB]; pb1b = p.pb1[nB]; }

  // streamed (not staged): whh rows
  const int rowL = q * 128 + jL;
  const float* whh0 = p.aW_hh0 + (size_t)rowL * 128;
  const float* whh1 = p.aW_hh1 + (size_t)rowL * 128;

  float* slotA = lds;              // {LSTM0, aRNN0, pol1}
  float* slotB = lds + SLOT_FL;    // {pol0, LSTM1, aRNN1}
  const int xrL = q << 1;          // LSTM weight swizzle
  const int xrP = nAr & 7;         // pol weight swizzle (same for nA and nB rows)

  float creg0 = 0.f, creg1 = 0.f;

  // ---- prologue: stage LSTM0 -> slotA (drained by first xbar) ----
  stage_lstm(p.aW_ih0, slotA, r, wv, lane);

  int e = 1;
  xbar(cnt, ep, e, tid);

  for (int t = 0; t < TT; ++t) {
    const int old = t & 1, nw = old ^ 1;
    float* ahx0_o = xb + XA0 + old * 1024;
    float* ahx0_n = xb + XA0 + nw  * 1024;
    float* ahx1_o = xb + XA1 + old * 1024;
    float* ahx1_n = xb + XA1 + nw  * 1024;
    float* fhx0_o = xb + XF0 + old * 4096;
    float* fhx0_n = xb + XF0 + nw  * 4096;
    float* fhx1_o = xb + XF1 + old * 4096;
    float* fhx1_n = xb + XF1 + nw  * 4096;
    float* pol0   = xb + XP0;
    float* pol1   = xb + XP1;
    const float* xt = p.x + ((size_t)t * 64 + b0) * 512;

    // ---- P0: LSTM0 (slotA) ; stage pol0 -> slotB ----
    stage_pol(p.pW0, slotB, r, wv, lane);
    {
      const float4* Lr = (const float4*)(slotA + (q * 4 + jj) * 1152);
      float s = dot_lx(xt     + blL * 512, Lr,        32, ks, xrL)
              + dot_lx(fhx0_o + blL * 512, Lr + 128,  32, ks, xrL)
              + dot_lx(ahx1_o + blL * 128, Lr + 256,   8, ks, xrL)
              + dot_ks(ahx0_o + blL * 128, whh0,       8, ks);
      s += __shfl_xor(s, 1); s += __shfl_xor(s, 2);
      float gi = __shfl(s,(lane&48)+0),  gf = __shfl(s,(lane&48)+4);
      float gg = __shfl(s,(lane&48)+8),  go = __shfl(s,(lane&48)+12);
      if (cell) {
        gi += bi0; gf += bf0; gg += bg0; go += bo0;
        float c2 = sigm(gf) * creg0 + sigm(gi) * tanhf(gg);
        creg0 = c2;
        ahx0_n[blL * 128 + jL] = sigm(go) * tanhf(c2);
      }
    }
    ++e; xbar(cnt, ep, e, tid);

    // ---- P1: pol0 (slotB) ; stage aRNN0 -> slotA ----
    stage_arnn(p.fW_ih0, p.fW_hh0, slotA, r, wv, lane);
    {
      pol0[blP * 2560 + nA] = pb0a +
          dot_pol(ahx0_n + blP * 128, slotB + nAr * 128, xrP);
      if (tid < 128)
        pol0[blP * 2560 + nB] = pb0b +
            dot_pol(ahx0_n + blP * 128, slotB + (64 + nAr) * 128, xrP);
    }
    ++e; xbar(cnt, ep, e, tid);

    // ---- P2: aRNN0 (slotA) ; stage LSTM1 -> slotB ----
    stage_lstm(p.aW_ih1, slotB, r, wv, lane);
    {
      const float* wi = slotA + c4 * 512;
      const float* wh = slotA + (16 + c4) * 512;
      const float* pr = pol0 + blA * 2560;
      float sig = dot3_ks(xt     + blA * 512, pr,       wi, 32, ks);
      float shg = dot3_ks(fhx0_o + blA * 512, pr + 512, wh, 32, ks);
      sig += __shfl_xor(sig, 1); sig += __shfl_xor(sig, 2);
      shg += __shfl_xor(shg, 1); shg += __shfl_xor(shg, 2);
      if (ks == 0) {
        float v = tanhf(sig * pr[1024 + cA] + fb0c * pr[2048 + cA]
                      + shg * pr[1536 + cA]);
        fhx0_n[blA * 512 + cA] = v;
      }
    }
    ++e; xbar(cnt, ep, e, tid);

    // ---- P3: LSTM1 (slotB) ; stage pol1 -> slotA ----
    stage_pol(p.pW1, slotA, r, wv, lane);
    {
      const float4* Lr = (const float4*)(slotB + (q * 4 + jj) * 1152);
      float s = dot_lx(fhx0_n + blL * 512, Lr,        32, ks, xrL)
              + dot_lx(fhx1_o + blL * 512, Lr + 128,  32, ks, xrL)
              + dot_lx(ahx0_n + blL * 128, Lr + 256,   8, ks, xrL)
              + dot_ks(ahx1_o + blL * 128, whh1,       8, ks);
      s += __shfl_xor(s, 1); s += __shfl_xor(s, 2);
      float gi = __shfl(s,(lane&48)+0),  gf = __shfl(s,(lane&48)+4);
      float gg = __shfl(s,(lane&48)+8),  go = __shfl(s,(lane&48)+12);
      if (cell) {
        gi += bi1; gf += bf1; gg += bg1; go += bo1;
        float c2 = sigm(gf) * creg1 + sigm(gi) * tanhf(gg);
        creg1 = c2;
        ahx1_n[blL * 128 + jL] = sigm(go) * tanhf(c2);
      }
    }
    ++e; xbar(cnt, ep, e, tid);

    // ---- P4: pol1 (slotA) ; stage aRNN1 -> slotB ----
    stage_arnn(p.fW_ih1, p.fW_hh1, slotB, r, wv, lane);
    {
      pol1[blP * 2560 + nA] = pb1a +
          dot_pol(ahx1_n + blP * 128, slotA + nAr * 128, xrP);
      if (tid < 128)
        pol1[blP * 2560 + nB] = pb1b +
            dot_pol(ahx1_n + blP * 128, slotA + (64 + nAr) * 128, xrP);
    }
    ++e; xbar(cnt, ep, e, tid);

    // ---- P5: aRNN1 + output (slotB) ; stage LSTM0 -> slotA (next step) ----
    stage_lstm(p.aW_ih0, slotA, r, wv, lane);
    {
      const float* wi = slotB + c4 * 512;
      const float* wh = slotB + (16 + c4) * 512;
      const float* pr = pol1 + blA * 2560;
      float sig = dot3_ks(fhx0_n + blA * 512, pr,       wi, 32, ks);
      float shg = dot3_ks(fhx1_o + blA * 512, pr + 512, wh, 32, ks);
      sig += __shfl_xor(sig, 1); sig += __shfl_xor(sig, 2);
      shg += __shfl_xor(shg, 1); shg += __shfl_xor(shg, 2);
      if (ks == 0) {
        float v = tanhf(sig * pr[1024 + cA] + fb1c * pr[2048 + cA]
                      + shg * pr[1536 + cA]);
        fhx1_n[blA * 512 + cA] = v;
        p.out[((size_t)t * 64 + b0 + blA) * 512 + cA] = v;
      }
    }
    ++e; xbar(cnt, ep, e, tid);
  }
}

extern "C" void kernel_launch(void* const* d_in, const int* in_sizes, int n_in,
                              void* d_out, int out_size, void* d_ws, size_t ws_size,
                              hipStream_t stream) {
  Params prm;
  prm.x      = (const float*)d_in[0];
  prm.aW_ih0 = (const float*)d_in[1];
  prm.aW_hh0 = (const float*)d_in[2];
  prm.ab_ih0 = (const float*)d_in[3];
  prm.ab_hh0 = (const float*)d_in[4];
  prm.pW0    = (const float*)d_in[5];
  prm.pb0    = (const float*)d_in[6];
  prm.fW_ih0 = (const float*)d_in[7];
  prm.fW_hh0 = (const float*)d_in[8];
  prm.fb0    = (const float*)d_in[9];
  prm.aW_ih1 = (const float*)d_in[10];
  prm.aW_hh1 = (const float*)d_in[11];
  prm.ab_ih1 = (const float*)d_in[12];
  prm.ab_hh1 = (const float*)d_in[13];
  prm.pW1    = (const float*)d_in[14];
  prm.pb1    = (const float*)d_in[15];
  prm.fW_ih1 = (const float*)d_in[16];
  prm.fW_hh1 = (const float*)d_in[17];
  prm.fb1    = (const float*)d_in[18];
  prm.out    = (float*)d_out;
  prm.ws     = (float*)d_ws;

  hipMemsetAsync((char*)d_ws + (size_t)O_BARB * 4, 0, 16384, stream);

  static int lds_bytes = 2 * SLOT_FL * 4;   // 144 KB -> 1 WG/CU
  hipFuncSetAttribute((const void*)arnn_kernel,
                      hipFuncAttributeMaxDynamicSharedMemorySize, lds_bytes);

  void* kargs[] = { (void*)&prm };
  hipLaunchCooperativeKernel((const void*)arnn_kernel, dim3(NWG), dim3(NTHR),
                             kargs, lds_bytes, stream);
}